// Round 4
// baseline (150.462 us; speedup 1.0000x reference)
//
#include <hip/hip_runtime.h>
#include <hip/hip_bf16.h>

typedef __attribute__((ext_vector_type(8))) short bf16x8;
typedef __attribute__((ext_vector_type(4))) float f32x4;
typedef __attribute__((ext_vector_type(4))) int   i32x4;
typedef __attribute__((ext_vector_type(2))) int   i32x2;

#define DEV static __device__ __forceinline__

DEV unsigned short f2bf(float f) {
  __hip_bfloat16 h = __float2bfloat16(f);
  return __builtin_bit_cast(unsigned short, h);
}
DEV int pack2(float a, float b) {
  return (int)f2bf(a) | ((int)f2bf(b) << 16);
}
DEV bf16x8 ldsFrag(const char* lds, int off) {
  i32x4 v = *(const i32x4*)(lds + off);
  return __builtin_bit_cast(bf16x8, v);
}

// ---------------- pre-kernel: blocks 0..511 transpose+cvt x -> xt[bc][u][m] bf16;
//                  blocks 512..1151 stream-cvt sw (512 blk) and tw (128 blk) to bf16
__global__ __launch_bounds__(256) void cvt_all(
    const float* __restrict__ x, unsigned short* __restrict__ xt,
    const float* __restrict__ sw, unsigned short* __restrict__ swb,
    const float* __restrict__ tw, unsigned short* __restrict__ twb)
{
  const int bid = blockIdx.x;
  const int tid = threadIdx.x;
  if (bid < 512) {
    __shared__ unsigned short lt[64][72];
    const int ut = bid & 3;          // u0 = ut*64
    const int mt = (bid >> 2) & 7;   // m0 = mt*64
    const int bc = bid >> 5;         // 0..15
    const int ul = tid & 63;
    const int mr = tid >> 6;
    const float* px = x + ((size_t)bc * 512 + mt * 64) * 256 + ut * 64;
#pragma unroll
    for (int r = 0; r < 16; r++) {
      int m = r * 4 + mr;
      lt[m][ul] = f2bf(px[(size_t)m * 256 + ul]);
    }
    __syncthreads();
    const int urow = tid >> 2;
    const int mq = tid & 3;
    unsigned short* po = xt + ((size_t)bc * 256 + ut * 64 + urow) * 512 + mt * 64 + mq * 16;
    int w[8];
#pragma unroll
    for (int j = 0; j < 8; j++) {
      unsigned short a = lt[mq * 16 + 2 * j][urow];
      unsigned short b = lt[mq * 16 + 2 * j + 1][urow];
      w[j] = (int)a | ((int)b << 16);
    }
    ((i32x4*)po)[0] = i32x4{w[0], w[1], w[2], w[3]};
    ((i32x4*)po)[1] = i32x4{w[4], w[5], w[6], w[7]};
  } else {
    int i = (bid - 512) * 256 + tid;
    const float* in;
    unsigned short* o;
    if (i < 131072) { in = sw; o = swb; }
    else            { in = tw; o = twb; i -= 131072; }
    const f32x4* p = (const f32x4*)(in + (size_t)i * 8);
    f32x4 a = p[0], b = p[1];
    i32x4 w;
    w[0] = pack2(a[0], a[1]); w[1] = pack2(a[2], a[3]);
    w[2] = pack2(b[0], b[1]); w[3] = pack2(b[2], b[3]);
    *(i32x4*)(o + (size_t)i * 8) = w;
  }
}

// ---------------- main fused kernel
// B=4, C=4, N=512, T=256, K(P)=4, J(Q)=4
// Block = (bc, p, n-tile of 64). Grid 512, 512 threads -> 2 blocks/CU, 32 waves/CU.
// Stage A: tmp[n][u] = sum_m S_p[n0+n][m] * X[m][u]   (acc = tmp^T frags, direct-global bf16)
// Stage B: C = mfma(A=T_q, B=tmp) -> C[t][n]; regs = 4 consecutive t -> dwordx4 stores.
__global__ __launch_bounds__(512, 4) void stblis_main(
    const unsigned short* __restrict__ xt, const unsigned short* __restrict__ swb,
    const unsigned short* __restrict__ twb, float* __restrict__ out)
{
  constexpr int N = 512, T = 256;
  // LDS: tmp[n=64][u=256] bf16, row 512B, slot s=(u>>3)^(n&7)
  __shared__ __align__(16) char lds[32768];

  const int tid  = threadIdx.x;
  const int lane = tid & 63;
  const int wid  = tid >> 6;
  const int l15  = lane & 15;
  const int l4   = lane >> 4;

  const int bx = blockIdx.x;
  const int nt = bx & 7;          // n-tile of 64
  const int p  = (bx >> 3) & 3;
  const int bc = bx >> 5;         // b*4 + c
  const int n0 = nt * 64;

  const unsigned short* __restrict__ Xu = xt  + (size_t)bc * (256 * 512);      // [u][m]
  const unsigned short* __restrict__ Sn = swb + (size_t)p * (N * N) + (size_t)n0 * N;

  // ---------------- stage A ----------------
  const int wu = wid >> 1;   // u block of 64
  const int wn = wid & 1;    // n block of 32

  f32x4 acc[4][2];
#pragma unroll
  for (int i = 0; i < 4; i++)
#pragma unroll
    for (int j = 0; j < 2; j++) acc[i][j] = {0.f, 0.f, 0.f, 0.f};

  const unsigned short* pxu = Xu + (size_t)(wu * 64 + l15) * 512 + l4 * 8;
  const unsigned short* psn = Sn + (size_t)(wn * 32 + l15) * 512 + l4 * 8;

  for (int kc = 0; kc < 8; kc++) {
#pragma unroll
    for (int ks = 0; ks < 2; ks++) {
      const int mofs = kc * 64 + ks * 32;
      bf16x8 af[4], bg[2];
#pragma unroll
      for (int uf = 0; uf < 4; uf++)
        af[uf] = *(const bf16x8*)(pxu + (size_t)uf * 16 * 512 + mofs);
#pragma unroll
      for (int nf = 0; nf < 2; nf++)
        bg[nf] = *(const bf16x8*)(psn + (size_t)nf * 16 * 512 + mofs);
#pragma unroll
      for (int uf = 0; uf < 4; uf++)
#pragma unroll
        for (int nf = 0; nf < 2; nf++)
          acc[uf][nf] = __builtin_amdgcn_mfma_f32_16x16x32_bf16(
              af[uf], bg[nf], acc[uf][nf], 0, 0, 0);
    }
  }

  // acc (tmp^T frags: row=u, col=n) -> LDS tmp[n][u] bf16
#pragma unroll
  for (int uf = 0; uf < 4; uf++)
#pragma unroll
    for (int nf = 0; nf < 2; nf++) {
      int u0 = wu * 64 + uf * 16 + l4 * 4;
      int n  = wn * 32 + nf * 16 + l15;
      i32x2 w;
      w[0] = pack2(acc[uf][nf][0], acc[uf][nf][1]);
      w[1] = pack2(acc[uf][nf][2], acc[uf][nf][3]);
      *(i32x2*)(lds + n * 512 + (((u0 >> 3) ^ (n & 7)) << 4) + (u0 & 7) * 2) = w;
    }
  __syncthreads();

  // ---------------- stage B ----------------
  const int q  = wid >> 1;
  const int nh = wid & 1;        // n half of 32
  const unsigned short* __restrict__ Tq = twb + (size_t)q * (T * T);  // [t][u]
  const int b = bc >> 2, c = bc & 3;
  const int ch = c * 16 + p * 4 + q;          // in [0,64)
  float* __restrict__ outP = out + ((size_t)(b * 128 + ch) * N + n0) * T;
  float* __restrict__ outN = outP + (size_t)64 * N * T;

  for (int tc = 0; tc < 4; tc++) {
    f32x4 a2[4][2];   // [tf][nf]
#pragma unroll
    for (int i = 0; i < 4; i++)
#pragma unroll
      for (int j = 0; j < 2; j++) a2[i][j] = {0.f, 0.f, 0.f, 0.f};

#pragma unroll
    for (int us = 0; us < 8; us++) {
      const int slot = us * 4 + l4;    // u-slot 0..31
      bf16x8 af[2], bg[4];
#pragma unroll
      for (int nf = 0; nf < 2; nf++) {
        int n = nh * 32 + nf * 16 + l15;
        af[nf] = ldsFrag(lds, n * 512 + ((slot ^ (n & 7)) << 4));
      }
#pragma unroll
      for (int tf = 0; tf < 4; tf++) {
        int t = tc * 64 + tf * 16 + l15;
        bg[tf] = *(const bf16x8*)(Tq + (size_t)t * T + slot * 8);
      }
#pragma unroll
      for (int tf = 0; tf < 4; tf++)
#pragma unroll
        for (int nf = 0; nf < 2; nf++)
          a2[tf][nf] = __builtin_amdgcn_mfma_f32_16x16x32_bf16(
              bg[tf], af[nf], a2[tf][nf], 0, 0, 0);   // C[row=t][col=n]
    }

    // epilogue: regs are 4 consecutive t -> one dwordx4 per frag, non-temporal
#pragma unroll
    for (int tf = 0; tf < 4; tf++) {
#pragma unroll
      for (int nf = 0; nf < 2; nf++) {
        int n  = nh * 32 + nf * 16 + l15;
        int t0 = tc * 64 + tf * 16 + l4 * 4;
        f32x4 v = a2[tf][nf];
        f32x4 vP, vN;
#pragma unroll
        for (int r = 0; r < 4; r++) {
          vP[r] = fmaxf(v[r], 0.f);
          vN[r] = fmaxf(-v[r], 0.f);
        }
        size_t o = (size_t)n * T + t0;
        __builtin_nontemporal_store(vP, (f32x4*)(outP + o));
        __builtin_nontemporal_store(vN, (f32x4*)(outN + o));
      }
    }
  }
}

extern "C" void kernel_launch(void* const* d_in, const int* in_sizes, int n_in,
                              void* d_out, int out_size, void* d_ws, size_t ws_size,
                              hipStream_t stream) {
  (void)in_sizes; (void)n_in; (void)out_size; (void)ws_size;
  const float* x  = (const float*)d_in[0];
  const float* sw = (const float*)d_in[1];
  const float* tw = (const float*)d_in[2];
  float* out = (float*)d_out;

  // workspace (bf16): xt 16*256*512 (4 MB) | swb 4*512*512 (2 MB) | twb 4*256*256 (0.5 MB)
  unsigned short* xt  = (unsigned short*)d_ws;
  unsigned short* swb = xt + (size_t)16 * 256 * 512;
  unsigned short* twb = swb + (size_t)4 * 512 * 512;

  cvt_all<<<dim3(1152), dim3(256), 0, stream>>>(x, xt, sw, swb, tw, twb);
  stblis_main<<<dim3(512), dim3(512), 0, stream>>>(xt, swb, twb, out);
}

// Round 5
// 149.077 us; speedup vs baseline: 1.0093x; 1.0093x over previous
//
#include <hip/hip_runtime.h>
#include <hip/hip_bf16.h>

typedef __attribute__((ext_vector_type(8))) short bf16x8;
typedef __attribute__((ext_vector_type(4))) float f32x4;
typedef __attribute__((ext_vector_type(4))) int   i32x4;
typedef __attribute__((ext_vector_type(2))) int   i32x2;

#define DEV static __device__ __forceinline__

DEV unsigned short f2bf(float f) {
  __hip_bfloat16 h = __float2bfloat16(f);
  return __builtin_bit_cast(unsigned short, h);
}
DEV int pack2(float a, float b) {
  return (int)f2bf(a) | ((int)f2bf(b) << 16);
}
DEV bf16x8 ldsFrag(const char* lds, int off) {
  i32x4 v = *(const i32x4*)(lds + off);
  return __builtin_bit_cast(bf16x8, v);
}

// ---------------- pre-kernel: blocks 0..511 transpose+cvt x -> xt[bc][u][m] bf16;
//                  blocks 512..1151 stream-cvt sw (512 blk) and tw (128 blk) to bf16
__global__ __launch_bounds__(256) void cvt_all(
    const float* __restrict__ x, unsigned short* __restrict__ xt,
    const float* __restrict__ sw, unsigned short* __restrict__ swb,
    const float* __restrict__ tw, unsigned short* __restrict__ twb)
{
  const int bid = blockIdx.x;
  const int tid = threadIdx.x;
  if (bid < 512) {
    __shared__ unsigned short lt[64][72];
    const int ut = bid & 3;          // u0 = ut*64
    const int mt = (bid >> 2) & 7;   // m0 = mt*64
    const int bc = bid >> 5;         // 0..15
    const int ul = tid & 63;
    const int mr = tid >> 6;
    const float* px = x + ((size_t)bc * 512 + mt * 64) * 256 + ut * 64;
#pragma unroll
    for (int r = 0; r < 16; r++) {
      int m = r * 4 + mr;
      lt[m][ul] = f2bf(px[(size_t)m * 256 + ul]);
    }
    __syncthreads();
    const int urow = tid >> 2;
    const int mq = tid & 3;
    unsigned short* po = xt + ((size_t)bc * 256 + ut * 64 + urow) * 512 + mt * 64 + mq * 16;
    int w[8];
#pragma unroll
    for (int j = 0; j < 8; j++) {
      unsigned short a = lt[mq * 16 + 2 * j][urow];
      unsigned short b = lt[mq * 16 + 2 * j + 1][urow];
      w[j] = (int)a | ((int)b << 16);
    }
    ((i32x4*)po)[0] = i32x4{w[0], w[1], w[2], w[3]};
    ((i32x4*)po)[1] = i32x4{w[4], w[5], w[6], w[7]};
  } else {
    int i = (bid - 512) * 256 + tid;
    const float* in;
    unsigned short* o;
    if (i < 131072) { in = sw; o = swb; }
    else            { in = tw; o = twb; i -= 131072; }
    const f32x4* p = (const f32x4*)(in + (size_t)i * 8);
    f32x4 a = p[0], b = p[1];
    i32x4 w;
    w[0] = pack2(a[0], a[1]); w[1] = pack2(a[2], a[3]);
    w[2] = pack2(b[0], b[1]); w[3] = pack2(b[2], b[3]);
    *(i32x4*)(o + (size_t)i * 8) = w;
  }
}

// ---------------- main fused kernel
// B=4, C=4, N=512, T=256, K(P)=4, J(Q)=4
// Block = (bc, p, n-tile of 64). Grid 512, 512 threads -> 2 blocks/CU.
// Stage A: tmp[n][u] = sum_m S_p[n0+n][m] * X[m][u]   (acc = tmp^T frags, direct-global bf16)
// Stage B: C = mfma(A=T_q, B=tmp) -> C[t][n]; regs = 4 consecutive t -> dwordx4 stores.
// Stores: PLAIN (L2-allocating) — NT was the suspected write-efficiency killer.
__global__ __launch_bounds__(512, 4) void stblis_main(
    const unsigned short* __restrict__ xt, const unsigned short* __restrict__ swb,
    const unsigned short* __restrict__ twb, float* __restrict__ out)
{
  constexpr int N = 512, T = 256;
  // LDS: tmp[n=64][u=256] bf16, row 512B, slot s=(u>>3)^(n&7)
  __shared__ __align__(16) char lds[32768];

  const int tid  = threadIdx.x;
  const int lane = tid & 63;
  const int wid  = tid >> 6;
  const int l15  = lane & 15;
  const int l4   = lane >> 4;

  const int bx = blockIdx.x;
  const int nt = bx & 7;          // n-tile of 64
  const int p  = (bx >> 3) & 3;
  const int bc = bx >> 5;         // b*4 + c
  const int n0 = nt * 64;

  const unsigned short* __restrict__ Xu = xt  + (size_t)bc * (256 * 512);      // [u][m]
  const unsigned short* __restrict__ Sn = swb + (size_t)p * (N * N) + (size_t)n0 * N;

  // ---------------- stage A ----------------
  const int wu = wid >> 1;   // u block of 64
  const int wn = wid & 1;    // n block of 32

  f32x4 acc[4][2];
#pragma unroll
  for (int i = 0; i < 4; i++)
#pragma unroll
    for (int j = 0; j < 2; j++) acc[i][j] = {0.f, 0.f, 0.f, 0.f};

  const unsigned short* pxu = Xu + (size_t)(wu * 64 + l15) * 512 + l4 * 8;
  const unsigned short* psn = Sn + (size_t)(wn * 32 + l15) * 512 + l4 * 8;

  for (int kc = 0; kc < 8; kc++) {
#pragma unroll
    for (int ks = 0; ks < 2; ks++) {
      const int mofs = kc * 64 + ks * 32;
      bf16x8 af[4], bg[2];
#pragma unroll
      for (int uf = 0; uf < 4; uf++)
        af[uf] = *(const bf16x8*)(pxu + (size_t)uf * 16 * 512 + mofs);
#pragma unroll
      for (int nf = 0; nf < 2; nf++)
        bg[nf] = *(const bf16x8*)(psn + (size_t)nf * 16 * 512 + mofs);
#pragma unroll
      for (int uf = 0; uf < 4; uf++)
#pragma unroll
        for (int nf = 0; nf < 2; nf++)
          acc[uf][nf] = __builtin_amdgcn_mfma_f32_16x16x32_bf16(
              af[uf], bg[nf], acc[uf][nf], 0, 0, 0);
    }
  }

  // acc (tmp^T frags: row=u, col=n) -> LDS tmp[n][u] bf16
#pragma unroll
  for (int uf = 0; uf < 4; uf++)
#pragma unroll
    for (int nf = 0; nf < 2; nf++) {
      int u0 = wu * 64 + uf * 16 + l4 * 4;
      int n  = wn * 32 + nf * 16 + l15;
      i32x2 w;
      w[0] = pack2(acc[uf][nf][0], acc[uf][nf][1]);
      w[1] = pack2(acc[uf][nf][2], acc[uf][nf][3]);
      *(i32x2*)(lds + n * 512 + (((u0 >> 3) ^ (n & 7)) << 4) + (u0 & 7) * 2) = w;
    }
  __syncthreads();

  // ---------------- stage B ----------------
  const int q  = wid >> 1;
  const int nh = wid & 1;        // n half of 32
  const unsigned short* __restrict__ Tq = twb + (size_t)q * (T * T);  // [t][u]
  const int b = bc >> 2, c = bc & 3;
  const int ch = c * 16 + p * 4 + q;          // in [0,64)
  float* __restrict__ outP = out + ((size_t)(b * 128 + ch) * N + n0) * T;
  float* __restrict__ outN = outP + (size_t)64 * N * T;

  for (int tc = 0; tc < 4; tc++) {
    f32x4 a2[4][2];   // [tf][nf]
#pragma unroll
    for (int i = 0; i < 4; i++)
#pragma unroll
      for (int j = 0; j < 2; j++) a2[i][j] = {0.f, 0.f, 0.f, 0.f};

#pragma unroll
    for (int us = 0; us < 8; us++) {
      const int slot = us * 4 + l4;    // u-slot 0..31
      bf16x8 af[2], bg[4];
#pragma unroll
      for (int nf = 0; nf < 2; nf++) {
        int n = nh * 32 + nf * 16 + l15;
        af[nf] = ldsFrag(lds, n * 512 + ((slot ^ (n & 7)) << 4));
      }
#pragma unroll
      for (int tf = 0; tf < 4; tf++) {
        int t = tc * 64 + tf * 16 + l15;
        bg[tf] = *(const bf16x8*)(Tq + (size_t)t * T + slot * 8);
      }
#pragma unroll
      for (int tf = 0; tf < 4; tf++)
#pragma unroll
        for (int nf = 0; nf < 2; nf++)
          a2[tf][nf] = __builtin_amdgcn_mfma_f32_16x16x32_bf16(
              bg[tf], af[nf], a2[tf][nf], 0, 0, 0);   // C[row=t][col=n]
    }

    // epilogue: regs are 4 consecutive t -> one dwordx4 per frag, PLAIN stores
#pragma unroll
    for (int tf = 0; tf < 4; tf++) {
#pragma unroll
      for (int nf = 0; nf < 2; nf++) {
        int n  = nh * 32 + nf * 16 + l15;
        int t0 = tc * 64 + tf * 16 + l4 * 4;
        f32x4 v = a2[tf][nf];
        f32x4 vP, vN;
#pragma unroll
        for (int r = 0; r < 4; r++) {
          vP[r] = fmaxf(v[r], 0.f);
          vN[r] = fmaxf(-v[r], 0.f);
        }
        size_t o = (size_t)n * T + t0;
        *(f32x4*)(outP + o) = vP;
        *(f32x4*)(outN + o) = vN;
      }
    }
  }
}

extern "C" void kernel_launch(void* const* d_in, const int* in_sizes, int n_in,
                              void* d_out, int out_size, void* d_ws, size_t ws_size,
                              hipStream_t stream) {
  (void)in_sizes; (void)n_in; (void)out_size; (void)ws_size;
  const float* x  = (const float*)d_in[0];
  const float* sw = (const float*)d_in[1];
  const float* tw = (const float*)d_in[2];
  float* out = (float*)d_out;

  // workspace (bf16): xt 16*256*512 (4 MB) | swb 4*512*512 (2 MB) | twb 4*256*256 (0.5 MB)
  unsigned short* xt  = (unsigned short*)d_ws;
  unsigned short* swb = xt + (size_t)16 * 256 * 512;
  unsigned short* twb = swb + (size_t)4 * 512 * 512;

  cvt_all<<<dim3(1152), dim3(256), 0, stream>>>(x, xt, sw, swb, tw, twb);
  stblis_main<<<dim3(512), dim3(512), 0, stream>>>(xt, swb, twb, out);
}

// Round 6
// 71.874 us; speedup vs baseline: 2.0934x; 2.0741x over previous
//
#include <hip/hip_runtime.h>
#include <hip/hip_bf16.h>

typedef __attribute__((ext_vector_type(8))) short bf16x8;
typedef __attribute__((ext_vector_type(4))) float f32x4;
typedef __attribute__((ext_vector_type(4))) int   i32x4;
typedef __attribute__((ext_vector_type(2))) int   i32x2;

#define DEV static __device__ __forceinline__

DEV unsigned short f2bf(float f) {
  __hip_bfloat16 h = __float2bfloat16(f);
  return __builtin_bit_cast(unsigned short, h);
}
DEV int pack2(float a, float b) {
  return (int)f2bf(a) | ((int)f2bf(b) << 16);
}
DEV bf16x8 ldsFrag(const char* lds, int off) {
  i32x4 v = *(const i32x4*)(lds + off);
  return __builtin_bit_cast(bf16x8, v);
}

// Tiled operand layout: each 1KB tile = one MFMA fragment set for a full wave,
// element order = lane-linear (lane l's 16B at tile_base + l*16B).
// A-frag tile [16 rows][32 k]: lane l -> (row = l&15, k = (l>>4)*8 + j)
// B-frag tile [16 cols][32 k]: identical order.

// ---------------- pre-kernel ----------------
// blocks 0..511:    x [bc][m=512][u=256] f32 -> xt tiles [bc][ut2=16][mt2=16][512 u16]
//                   (A-frag for stage A: row=u, k=m  -> transpose via LDS)
// blocks 512..1023: sw [p][n=512][m=512] f32 -> swb tiles [p*32+nt2][mt2][512 u16] (B-frag: col=n,k=m)
// blocks 1024..1151: tw [q][t=256][u=256] f32 -> twb tiles [(q*16+tt2)*8+ut2][512 u16] (A-frag: row=t,k=u)
__global__ __launch_bounds__(256) void cvt_all(
    const float* __restrict__ x, unsigned short* __restrict__ xt,
    const float* __restrict__ sw, unsigned short* __restrict__ swb,
    const float* __restrict__ tw, unsigned short* __restrict__ twb)
{
  const int bid = blockIdx.x;
  const int tid = threadIdx.x;
  if (bid < 512) {
    __shared__ unsigned short lt[64][72];
    const int ut = bid & 3;          // u group of 64
    const int mt = (bid >> 2) & 7;   // m group of 64
    const int bc = bid >> 5;         // 0..15
    const int ul = tid & 63;
    const int mr = tid >> 6;
    const float* px = x + ((size_t)bc * 512 + mt * 64) * 256 + ut * 64;
#pragma unroll
    for (int r = 0; r < 16; r++) {
      int m = r * 4 + mr;
      lt[m][ul] = f2bf(px[(size_t)m * 256 + ul]);
    }
    __syncthreads();
    // 8 tiles per block: a = u-tile (4), bb = m-tile (2)
    const int t8 = tid >> 5;
    const int a  = t8 & 3;
    const int bb = t8 >> 2;
    const int l0 = tid & 31;
    unsigned short* tilep =
        xt + (((size_t)(bc * 16 + ut * 4 + a)) * 16 + (mt * 2 + bb)) * 512;
#pragma unroll
    for (int h = 0; h < 2; h++) {
      int l = l0 + h * 32;
      int ur = a * 16 + (l & 15);
      int mb = bb * 32 + (l >> 4) * 8;
      i32x4 w;
#pragma unroll
      for (int j = 0; j < 4; j++)
        w[j] = (int)lt[mb + 2 * j][ur] | ((int)lt[mb + 2 * j + 1][ur] << 16);
      *(i32x4*)(tilep + l * 8) = w;
    }
  } else if (bid < 1024) {
    const int tile = (bid - 512) * 4 + (tid >> 6);
    const int l = tid & 63;
    const int mt2 = tile & 15;
    const int nt2 = (tile >> 4) & 31;
    const int p   = tile >> 9;
    const float* ps = sw + ((size_t)p * 512 + nt2 * 16 + (l & 15)) * 512
                         + mt2 * 32 + (l >> 4) * 8;
    f32x4 A = ((const f32x4*)ps)[0], Bv = ((const f32x4*)ps)[1];
    i32x4 w;
    w[0] = pack2(A[0], A[1]);  w[1] = pack2(A[2], A[3]);
    w[2] = pack2(Bv[0], Bv[1]); w[3] = pack2(Bv[2], Bv[3]);
    *(i32x4*)(swb + (size_t)tile * 512 + l * 8) = w;
  } else {
    const int tile = (bid - 1024) * 4 + (tid >> 6);
    const int l = tid & 63;
    const int ut2 = tile & 7;
    const int tt2 = (tile >> 3) & 15;
    const int q   = tile >> 7;
    const float* pt = tw + ((size_t)q * 256 + tt2 * 16 + (l & 15)) * 256
                         + ut2 * 32 + (l >> 4) * 8;
    f32x4 A = ((const f32x4*)pt)[0], Bv = ((const f32x4*)pt)[1];
    i32x4 w;
    w[0] = pack2(A[0], A[1]);  w[1] = pack2(A[2], A[3]);
    w[2] = pack2(Bv[0], Bv[1]); w[3] = pack2(Bv[2], Bv[3]);
    *(i32x4*)(twb + (size_t)tile * 512 + l * 8) = w;
  }
}

// ---------------- main fused kernel ----------------
// B=4, C=4, N=512, T=256, K(P)=4, J(Q)=4
// Block = (bc, p, n-tile of 64). Grid 512, 512 threads -> 2 blocks/CU.
// Stage A: tmp[n][u] = sum_m S_p[n0+n][m]*X[m][u] (acc = tmp^T frags; tiled-global loads)
// Stage B: 16 phases (q,tc); all 8 waves (tq x nh) compute C[t][n] = mfma(Tq, tmp),
//   stage y-tile (64n x 64t f32) in double-buffered swizzled LDS, then all 512 threads
//   store LINEARLY: lanes 0-15 cover one contiguous 256B row -> 8 full 128B lines/instr.
__global__ __launch_bounds__(512, 4) void stblis_main(
    const unsigned short* __restrict__ xt, const unsigned short* __restrict__ swb,
    const unsigned short* __restrict__ twb, float* __restrict__ out)
{
  // LDS: [0,32768) tmp[n=64][u=256] bf16, row 512B, slot s=(u>>3)^(n&7)
  //      [32768,49152) stg0: y f32 [64 n][16 chunks of 16B], chunk c at (c^(n&7))*16
  //      [49152,65536) stg1
  __shared__ __align__(16) char lds[65536];

  const int tid  = threadIdx.x;
  const int lane = tid & 63;
  const int wid  = tid >> 6;
  const int l15  = lane & 15;
  const int l4   = lane >> 4;

  const int bx = blockIdx.x;
  const int nt = bx & 7;          // n-tile of 64
  const int p  = (bx >> 3) & 3;
  const int bc = bx >> 5;         // b*4 + c
  const int n0 = nt * 64;

  // ---------------- stage A ----------------
  const int wu = wid >> 1;   // u block of 64
  const int wn = wid & 1;    // n block of 32

  f32x4 acc[4][2];
#pragma unroll
  for (int i = 0; i < 4; i++)
#pragma unroll
    for (int j = 0; j < 2; j++) acc[i][j] = {0.f, 0.f, 0.f, 0.f};

  const unsigned short* xA = xt  + (((size_t)(bc * 16 + wu * 4)) * 16) * 512 + lane * 8;
  const unsigned short* sB = swb + (((size_t)(p * 32 + nt * 4 + wn * 2)) * 16) * 512 + lane * 8;

  for (int kc = 0; kc < 8; kc++) {
#pragma unroll
    for (int ks = 0; ks < 2; ks++) {
      const int mt2 = kc * 2 + ks;
      bf16x8 af[4], bg[2];
#pragma unroll
      for (int uf = 0; uf < 4; uf++)
        af[uf] = *(const bf16x8*)(xA + ((size_t)uf * 16 + mt2) * 512);
#pragma unroll
      for (int nf = 0; nf < 2; nf++)
        bg[nf] = *(const bf16x8*)(sB + ((size_t)nf * 16 + mt2) * 512);
#pragma unroll
      for (int uf = 0; uf < 4; uf++)
#pragma unroll
        for (int nf = 0; nf < 2; nf++)
          acc[uf][nf] = __builtin_amdgcn_mfma_f32_16x16x32_bf16(
              af[uf], bg[nf], acc[uf][nf], 0, 0, 0);
    }
  }

  // acc (tmp^T frags: row=u, col=n) -> LDS tmp[n][u] bf16 (swizzled)
#pragma unroll
  for (int uf = 0; uf < 4; uf++)
#pragma unroll
    for (int nf = 0; nf < 2; nf++) {
      int u0 = wu * 64 + uf * 16 + l4 * 4;
      int n  = wn * 32 + nf * 16 + l15;
      i32x2 w;
      w[0] = pack2(acc[uf][nf][0], acc[uf][nf][1]);
      w[1] = pack2(acc[uf][nf][2], acc[uf][nf][3]);
      *(i32x2*)(lds + n * 512 + (((u0 >> 3) ^ (n & 7)) << 4) + (u0 & 7) * 2) = w;
    }
  __syncthreads();

  // ---------------- stage B: 16 phases ----------------
  const int tq = wid >> 1;       // t quarter (16 t)
  const int nh = wid & 1;        // n half (32 n)
  const int b = bc >> 2, c = bc & 3;

  for (int ph = 0; ph < 16; ph++) {
    const int q  = ph >> 2;
    const int tc = ph & 3;
    char* stgW = lds + 32768 + (ph & 1) * 16384;

    // MFMA: wave computes (t = tc*64 + tq*16 + [0,16), n = nh*32 + [0,32))
    f32x4 a2[2];
    a2[0] = {0.f, 0.f, 0.f, 0.f};
    a2[1] = {0.f, 0.f, 0.f, 0.f};
    const unsigned short* tA =
        twb + (((size_t)(q * 16 + tc * 4 + tq)) * 8) * 512 + lane * 8;
#pragma unroll
    for (int us = 0; us < 8; us++) {
      bf16x8 bg = *(const bf16x8*)(tA + (size_t)us * 512);
#pragma unroll
      for (int nf = 0; nf < 2; nf++) {
        int n = nh * 32 + nf * 16 + l15;
        bf16x8 af = ldsFrag(lds, n * 512 + ((((us * 4 + l4)) ^ (n & 7)) << 4));
        a2[nf] = __builtin_amdgcn_mfma_f32_16x16x32_bf16(bg, af, a2[nf], 0, 0, 0);
      }
    }
    // stage y-frags to LDS: lane's 4 regs = 4 consecutive t -> one 16B chunk
#pragma unroll
    for (int nf = 0; nf < 2; nf++) {
      int n = nh * 32 + nf * 16 + l15;
      int c16 = tq * 4 + l4;
      *(f32x4*)(stgW + n * 256 + ((c16 ^ (n & 7)) << 4)) = a2[nf];
    }
    __syncthreads();

    // linear store: lanes 0..15 cover a full 256B row (2 full lines)
    float* outQP = out + ((size_t)(b * 128 + c * 16 + p * 4 + q) * 512 + n0) * 256;
    float* outQN = outQP + (size_t)64 * 512 * 256;
#pragma unroll
    for (int h = 0; h < 2; h++) {
      int cc  = tid + h * 512;
      int r   = cc >> 4;
      int o16 = cc & 15;
      f32x4 y = *(const f32x4*)(stgW + r * 256 + ((o16 ^ (r & 7)) << 4));
      f32x4 vP, vN;
#pragma unroll
      for (int j = 0; j < 4; j++) {
        vP[j] = fmaxf(y[j], 0.f);
        vN[j] = fmaxf(-y[j], 0.f);
      }
      size_t go = (size_t)r * 256 + tc * 64 + o16 * 4;
      *(f32x4*)(outQP + go) = vP;
      *(f32x4*)(outQN + go) = vN;
    }
    // next phase writes the other stg buffer; one barrier per phase suffices
  }
}

extern "C" void kernel_launch(void* const* d_in, const int* in_sizes, int n_in,
                              void* d_out, int out_size, void* d_ws, size_t ws_size,
                              hipStream_t stream) {
  (void)in_sizes; (void)n_in; (void)out_size; (void)ws_size;
  const float* x  = (const float*)d_in[0];
  const float* sw = (const float*)d_in[1];
  const float* tw = (const float*)d_in[2];
  float* out = (float*)d_out;

  // workspace (u16 elements): xt 16*16*16*512 (4 MB) | swb 2048*512 (2 MB) | twb 512*512 (0.5 MB)
  unsigned short* xt  = (unsigned short*)d_ws;
  unsigned short* swb = xt + (size_t)16 * 16 * 16 * 512;
  unsigned short* twb = swb + (size_t)2048 * 512;

  cvt_all<<<dim3(1152), dim3(256), 0, stream>>>(x, xt, sw, swb, tw, twb);
  stblis_main<<<dim3(512), dim3(512), 0, stream>>>(xt, swb, twb, out);
}

// Round 7
// 70.691 us; speedup vs baseline: 2.1285x; 1.0167x over previous
//
#include <hip/hip_runtime.h>
#include <hip/hip_bf16.h>

typedef __attribute__((ext_vector_type(8))) short bf16x8;
typedef __attribute__((ext_vector_type(4))) float f32x4;
typedef __attribute__((ext_vector_type(4))) int   i32x4;
typedef __attribute__((ext_vector_type(2))) int   i32x2;

#define DEV static __device__ __forceinline__

DEV unsigned short f2bf(float f) {
  __hip_bfloat16 h = __float2bfloat16(f);
  return __builtin_bit_cast(unsigned short, h);
}
DEV int pack2(float a, float b) {
  return (int)f2bf(a) | ((int)f2bf(b) << 16);
}
DEV bf16x8 ldsFrag(const char* lds, int off) {
  i32x4 v = *(const i32x4*)(lds + off);
  return __builtin_bit_cast(bf16x8, v);
}

// Tiled operand layout: each 1KB tile = one MFMA fragment set for a full wave,
// element order = lane-linear (lane l's 16B at tile_base + l*16B).
// A-frag tile [16 rows][32 k]: lane l -> (row = l&15, k = (l>>4)*8 + j)
// B-frag tile [16 cols][32 k]: identical order.

// ---------------- pre-kernel ----------------
__global__ __launch_bounds__(256) void cvt_all(
    const float* __restrict__ x, unsigned short* __restrict__ xt,
    const float* __restrict__ sw, unsigned short* __restrict__ swb,
    const float* __restrict__ tw, unsigned short* __restrict__ twb)
{
  const int bid = blockIdx.x;
  const int tid = threadIdx.x;
  if (bid < 512) {
    __shared__ unsigned short lt[64][72];
    const int ut = bid & 3;          // u group of 64
    const int mt = (bid >> 2) & 7;   // m group of 64
    const int bc = bid >> 5;         // 0..15
    const int ul = tid & 63;
    const int mr = tid >> 6;
    const float* px = x + ((size_t)bc * 512 + mt * 64) * 256 + ut * 64;
#pragma unroll
    for (int r = 0; r < 16; r++) {
      int m = r * 4 + mr;
      lt[m][ul] = f2bf(px[(size_t)m * 256 + ul]);
    }
    __syncthreads();
    const int t8 = tid >> 5;
    const int a  = t8 & 3;
    const int bb = t8 >> 2;
    const int l0 = tid & 31;
    unsigned short* tilep =
        xt + (((size_t)(bc * 16 + ut * 4 + a)) * 16 + (mt * 2 + bb)) * 512;
#pragma unroll
    for (int h = 0; h < 2; h++) {
      int l = l0 + h * 32;
      int ur = a * 16 + (l & 15);
      int mb = bb * 32 + (l >> 4) * 8;
      i32x4 w;
#pragma unroll
      for (int j = 0; j < 4; j++)
        w[j] = (int)lt[mb + 2 * j][ur] | ((int)lt[mb + 2 * j + 1][ur] << 16);
      *(i32x4*)(tilep + l * 8) = w;
    }
  } else if (bid < 1024) {
    const int tile = (bid - 512) * 4 + (tid >> 6);
    const int l = tid & 63;
    const int mt2 = tile & 15;
    const int nt2 = (tile >> 4) & 31;
    const int p   = tile >> 9;
    const float* ps = sw + ((size_t)p * 512 + nt2 * 16 + (l & 15)) * 512
                         + mt2 * 32 + (l >> 4) * 8;
    f32x4 A = ((const f32x4*)ps)[0], Bv = ((const f32x4*)ps)[1];
    i32x4 w;
    w[0] = pack2(A[0], A[1]);  w[1] = pack2(A[2], A[3]);
    w[2] = pack2(Bv[0], Bv[1]); w[3] = pack2(Bv[2], Bv[3]);
    *(i32x4*)(swb + (size_t)tile * 512 + l * 8) = w;
  } else {
    const int tile = (bid - 1024) * 4 + (tid >> 6);
    const int l = tid & 63;
    const int ut2 = tile & 7;
    const int tt2 = (tile >> 3) & 15;
    const int q   = tile >> 7;
    const float* pt = tw + ((size_t)q * 256 + tt2 * 16 + (l & 15)) * 256
                         + ut2 * 32 + (l >> 4) * 8;
    f32x4 A = ((const f32x4*)pt)[0], Bv = ((const f32x4*)pt)[1];
    i32x4 w;
    w[0] = pack2(A[0], A[1]);  w[1] = pack2(A[2], A[3]);
    w[2] = pack2(Bv[0], Bv[1]); w[3] = pack2(Bv[2], Bv[3]);
    *(i32x4*)(twb + (size_t)tile * 512 + l * 8) = w;
  }
}

// ---------------- main fused kernel ----------------
// B=4, C=4, N=512, T=256, K(P)=4, J(Q)=4
// Block = (bc, p, n-tile of 64). Grid 512, 512 threads.
// Stage A: tmp[n][u] = sum_m S_p[n0+n][m]*X[m][u] (acc = tmp^T frags; tiled loads)
//   -> tmp in LDS [0,32768), then HOISTED to registers (afr[8][2], 64 VGPR).
// Stage B: 16 phases (q,tc); per phase: 16 reg-only MFMA -> ds_write y-tile
//   (staging DOUBLE-BUFFERED, aliased over dead tmp) -> barrier -> full-line stores.
//   Next phase's Tq fragments prefetched from global one phase ahead.
__global__ __launch_bounds__(512, 4) void stblis_main(
    const unsigned short* __restrict__ xt, const unsigned short* __restrict__ swb,
    const unsigned short* __restrict__ twb, float* __restrict__ out)
{
  // LDS: phase 1: tmp[n=64][u=256] bf16, row 512B, slot s=(u>>3)^(n&7)  [0,32768)
  //      phase 2: stg0 [0,16384), stg1 [16384,32768):
  //               y f32 [64 n][16 chunks of 16B], chunk c at (c^(n&7))*16
  __shared__ __align__(16) char lds[32768];

  const int tid  = threadIdx.x;
  const int lane = tid & 63;
  const int wid  = tid >> 6;
  const int l15  = lane & 15;
  const int l4   = lane >> 4;

  const int bx = blockIdx.x;
  const int nt = bx & 7;          // n-tile of 64
  const int p  = (bx >> 3) & 3;
  const int bc = bx >> 5;         // b*4 + c
  const int n0 = nt * 64;
  const int b = bc >> 2, c = bc & 3;

  // ---------------- stage A ----------------
  const int wu = wid >> 1;   // u block of 64
  const int wn = wid & 1;    // n block of 32

  f32x4 acc[4][2];
#pragma unroll
  for (int i = 0; i < 4; i++)
#pragma unroll
    for (int j = 0; j < 2; j++) acc[i][j] = {0.f, 0.f, 0.f, 0.f};

  const unsigned short* xA = xt  + (((size_t)(bc * 16 + wu * 4)) * 16) * 512 + lane * 8;
  const unsigned short* sB = swb + (((size_t)(p * 32 + nt * 4 + wn * 2)) * 16) * 512 + lane * 8;

  for (int kc = 0; kc < 8; kc++) {
#pragma unroll
    for (int ks = 0; ks < 2; ks++) {
      const int mt2 = kc * 2 + ks;
      bf16x8 af[4], bg[2];
#pragma unroll
      for (int uf = 0; uf < 4; uf++)
        af[uf] = *(const bf16x8*)(xA + ((size_t)uf * 16 + mt2) * 512);
#pragma unroll
      for (int nf = 0; nf < 2; nf++)
        bg[nf] = *(const bf16x8*)(sB + ((size_t)nf * 16 + mt2) * 512);
#pragma unroll
      for (int uf = 0; uf < 4; uf++)
#pragma unroll
        for (int nf = 0; nf < 2; nf++)
          acc[uf][nf] = __builtin_amdgcn_mfma_f32_16x16x32_bf16(
              af[uf], bg[nf], acc[uf][nf], 0, 0, 0);
    }
  }

  // acc (tmp^T frags: row=u, col=n) -> LDS tmp[n][u] bf16 (swizzled)
#pragma unroll
  for (int uf = 0; uf < 4; uf++)
#pragma unroll
    for (int nf = 0; nf < 2; nf++) {
      int u0 = wu * 64 + uf * 16 + l4 * 4;
      int n  = wn * 32 + nf * 16 + l15;
      i32x2 w;
      w[0] = pack2(acc[uf][nf][0], acc[uf][nf][1]);
      w[1] = pack2(acc[uf][nf][2], acc[uf][nf][3]);
      *(i32x2*)(lds + n * 512 + (((u0 >> 3) ^ (n & 7)) << 4) + (u0 & 7) * 2) = w;
    }
  __syncthreads();

  // ---------------- stage B ----------------
  const int tq = wid >> 1;       // t quarter (16 t)
  const int nh = wid & 1;        // n half (32 n)

#define LOADBG(dst, ph)                                                        \
  {                                                                            \
    const int q_ = (ph) >> 2, tc_ = (ph) & 3;                                  \
    const unsigned short* tA_ =                                                \
        twb + (((size_t)(q_ * 16 + tc_ * 4 + tq)) * 8) * 512 + lane * 8;       \
    _Pragma("unroll")                                                          \
    for (int us = 0; us < 8; us++)                                             \
      dst[us] = *(const bf16x8*)(tA_ + (size_t)us * 512);                      \
  }

  // prefetch phase-0 bg (global, overlaps the hoist ds_reads below)
  bf16x8 bgA[8], bgB[8];
  LOADBG(bgA, 0);

  // hoist tmp A-frags to registers: phase-invariant (depend on us, nf only)
  bf16x8 afr[8][2];
#pragma unroll
  for (int us = 0; us < 8; us++)
#pragma unroll
    for (int nf = 0; nf < 2; nf++) {
      int n = nh * 32 + nf * 16 + l15;
      afr[us][nf] = ldsFrag(lds, n * 512 + (((us * 4 + l4) ^ (n & 7)) << 4));
    }
  __syncthreads();   // tmp now dead; staging buffers alias it

  char* const stg0 = lds;
  char* const stg1 = lds + 16384;

  auto body = [&](int ph, bf16x8 (&bg)[8], char* stgW) {
    const int q  = ph >> 2;
    const int tc = ph & 3;
    f32x4 a2[2];
    a2[0] = {0.f, 0.f, 0.f, 0.f};
    a2[1] = {0.f, 0.f, 0.f, 0.f};
#pragma unroll
    for (int us = 0; us < 8; us++) {
      a2[0] = __builtin_amdgcn_mfma_f32_16x16x32_bf16(bg[us], afr[us][0], a2[0], 0, 0, 0);
      a2[1] = __builtin_amdgcn_mfma_f32_16x16x32_bf16(bg[us], afr[us][1], a2[1], 0, 0, 0);
    }
    // stage y-frags to LDS: lane's 4 regs = 4 consecutive t -> one 16B chunk
#pragma unroll
    for (int nf = 0; nf < 2; nf++) {
      int n = nh * 32 + nf * 16 + l15;
      int c16 = tq * 4 + l4;
      *(f32x4*)(stgW + n * 256 + ((c16 ^ (n & 7)) << 4)) = a2[nf];
    }
    __syncthreads();
    // linear store: lanes 0..15 cover a full 256B row (2 full 128B lines)
    float* outQP = out + ((size_t)(b * 128 + c * 16 + p * 4 + q) * 512 + n0) * 256;
    float* outQN = outQP + (size_t)64 * 512 * 256;
#pragma unroll
    for (int h = 0; h < 2; h++) {
      int cc  = tid + h * 512;
      int r   = cc >> 4;
      int o16 = cc & 15;
      f32x4 y = *(const f32x4*)(stgW + r * 256 + ((o16 ^ (r & 7)) << 4));
      f32x4 vP, vN;
#pragma unroll
      for (int j = 0; j < 4; j++) {
        vP[j] = fmaxf(y[j], 0.f);
        vN[j] = fmaxf(-y[j], 0.f);
      }
      size_t go = (size_t)r * 256 + tc * 64 + o16 * 4;
      *(f32x4*)(outQP + go) = vP;
      *(f32x4*)(outQN + go) = vN;
    }
    // WAR on stgW (phase ph+2's writes) is fenced by phase ph+1's barrier
  };

  for (int ph2 = 0; ph2 < 8; ph2++) {
    const int ph = ph2 * 2;
    LOADBG(bgB, ph + 1);          // prefetch: latency hides under body(ph)
    body(ph, bgA, stg0);
    if (ph2 < 7) LOADBG(bgA, ph + 2);
    body(ph + 1, bgB, stg1);
  }
#undef LOADBG
}

extern "C" void kernel_launch(void* const* d_in, const int* in_sizes, int n_in,
                              void* d_out, int out_size, void* d_ws, size_t ws_size,
                              hipStream_t stream) {
  (void)in_sizes; (void)n_in; (void)out_size; (void)ws_size;
  const float* x  = (const float*)d_in[0];
  const float* sw = (const float*)d_in[1];
  const float* tw = (const float*)d_in[2];
  float* out = (float*)d_out;

  // workspace (u16 elements): xt 16*16*16*512 (4 MB) | swb 2048*512 (2 MB) | twb 512*512 (0.5 MB)
  unsigned short* xt  = (unsigned short*)d_ws;
  unsigned short* swb = xt + (size_t)16 * 16 * 16 * 512;
  unsigned short* twb = swb + (size_t)2048 * 512;

  cvt_all<<<dim3(1152), dim3(256), 0, stream>>>(x, xt, sw, swb, tw, twb);
  stblis_main<<<dim3(512), dim3(512), 0, stream>>>(xt, swb, twb, out);
}